// Round 4
// baseline (391.272 us; speedup 1.0000x reference)
//
#include <hip/hip_runtime.h>
#include <stdint.h>

typedef unsigned short u16;
typedef short short8 __attribute__((ext_vector_type(8)));
typedef float floatx4 __attribute__((ext_vector_type(4)));

#define NPERB   40000
#define NPTS    80000
#define KNBR    16
#define CIN     64
#define MDIM    16
#define CADD    3
#define CF      (CIN + CADD)
#define COUT    128
#define KF      1072
#define KP      1088
#define NKT     34        // KP/32 K-steps
#define SLAB    65        // chunks per kt slab: 16 rows x 4 quads + 1 pad
#define PTSB    16        // points per block

__device__ __forceinline__ u16 f2bf(float f) {
    union { float f; unsigned int u; } v; v.f = f;
    unsigned int u = v.u;
    return (u16)((u + 0x7FFFu + ((u >> 16) & 1u)) >> 16);
}
__device__ __forceinline__ short8 pack8(floatx4 x, floatx4 y) {
    union { short8 v; u16 a[8]; } u;
    u.a[0] = f2bf(x[0]); u.a[1] = f2bf(x[1]); u.a[2] = f2bf(x[2]); u.a[3] = f2bf(x[3]);
    u.a[4] = f2bf(y[0]); u.a[5] = f2bf(y[1]); u.a[6] = f2bf(y[2]); u.a[7] = f2bf(y[3]);
    return u.v;
}

// Convert+pad linear_weight fp32 [128,1072] -> bf16 ws [128,1088] (zero pad).
__global__ void prep_lw_kernel(const float* __restrict__ lw, u16* __restrict__ lwp) {
    int i = blockIdx.x * 256 + threadIdx.x;
    if (i >= COUT * KP) return;
    int o = i / KP, f = i - o * KP;
    lwp[i] = (f < KF) ? f2bf(lw[(size_t)o * KF + f]) : (u16)0;
}

// Fused: phase 1 builds pconv for 16 points directly in LDS in MFMA-A chunk
// layout; phase 2 does the [16 x 1088] x [1088 x 128] GEMM with bf16 MFMA.
// Chunk (kt, pr, quad) holds pconv[point=pr][f = kt*32 + quad*8 .. +7] as 8
// bf16 (16 B). Chunk index = kt*SLAB + pr*4 + quad; SLAB=65 (+1 pad) makes the
// kt-stride 260 dwords === 4 (mod 32) so writes hit the bank floor.
__global__ __launch_bounds__(256) void fused_kernel(
    const float* __restrict__ inp,   // [2,40000,64] fp32
    const int*   __restrict__ nbr,   // [2,40000,16] int32
    const float* __restrict__ wn,    // [2,40000,16,16] fp32
    const float* __restrict__ addl,  // [2,40000,16,3] fp32
    const u16*   __restrict__ lwp,   // [128,1088] bf16 (padded)
    const float* __restrict__ bias,  // [128] fp32
    float* __restrict__ out)         // [80000,128] fp32
{
    __shared__ __align__(16) u16   Apc[NKT * SLAB * 8];       // 35360 B
    __shared__ __align__(16) float wsm[4][KNBR * MDIM];       // 4096 B

    const int wave = threadIdx.x >> 6;
    const int lane = threadIdx.x & 63;
    const int pbase = blockIdx.x * PTSB;
    const float* inpb = inp + ((pbase >= NPERB) ? (size_t)NPERB * CIN : 0);

    // ---------------- phase 1: pconv -> LDS ----------------
    for (int i = 0; i < PTSB / 4; i++) {
        const int pr = wave * 4 + i;            // point row 0..15
        const int p  = pbase + pr;

        // stage this point's weightnet into this wave's LDS scratch
        floatx4 w4 = ((const floatx4*)(wn + (size_t)p * (KNBR * MDIM)))[lane];
        *(floatx4*)&wsm[wave][lane * 4] = w4;

        // preload additional_features (48 floats) into lanes 0..47
        float av_hold = (lane < KNBR * CADD)
                          ? addl[(size_t)p * (KNBR * CADD) + lane] : 0.f;

        const int* nbrp = nbr + (size_t)p * KNBR;
        const floatx4* wrow = (const floatx4*)&wsm[wave][0];

        // main channels: lane = c (0..63)
        floatx4 a0 = 0, a1 = 0, a2 = 0, a3 = 0;
#pragma unroll
        for (int k = 0; k < KNBR; k++) {
            int idx = nbrp[k];                              // wave-uniform s_load
            float fv = inpb[(size_t)idx * CIN + lane];      // coalesced 256B/wave
            a0 += fv * wrow[k * 4 + 0];
            a1 += fv * wrow[k * 4 + 1];
            a2 += fv * wrow[k * 4 + 2];
            a3 += fv * wrow[k * 4 + 3];
        }
        {
            const int kt = lane >> 1, qb = (lane & 1) * 2;
            u16* ch = &Apc[(unsigned)(kt * SLAB + pr * 4 + qb) * 8];
            *(short8*)ch       = pack8(a0, a1);   // m 0..7
            *(short8*)(ch + 8) = pack8(a2, a3);   // m 8..15
        }

        // extra channels 64..67 (67 = zero pad): lane -> (c = lane>>4, m = lane&15)
        {
            const int ec = lane >> 4, em = lane & 15;
            float ev = 0.f;
#pragma unroll
            for (int k = 0; k < KNBR; k++) {
                float av = __shfl(av_hold, k * CADD + ec);
                ev += av * wsm[wave][k * MDIM + em];
            }
            if (ec == 3) ev = 0.f;                // channel 67 is pad
            const int kt = 32 + (lane >> 5), quad = (lane >> 3) & 3;
            Apc[(unsigned)(kt * SLAB + pr * 4 + quad) * 8 + (lane & 7)] = f2bf(ev);
        }
    }
    __syncthreads();

    // ---------------- phase 2: GEMM [16 x KP] x [KP x 128] ----------------
    // wave tile: 16 points x 32 cols, c0 = wave*32.
    // mfma_f32_16x16x32_bf16: A[i=lane&15][k=quad*8+j], B[k=quad*8+j][n=lane&15],
    // D[row=quad*4+r][col=lane&15]  (m89/m91-verified).
    const int r16 = lane & 15, quad = lane >> 4;
    const int c0 = wave * 32;
    const u16* B0p = lwp + (size_t)(c0 + r16) * KP + quad * 8;
    const u16* B1p = B0p + (size_t)16 * KP;

    floatx4 acc0 = 0, acc1 = 0;
#pragma unroll 2
    for (int kt = 0; kt < NKT; kt++) {
        short8 A  = *(const short8*)&Apc[(unsigned)(kt * SLAB + r16 * 4 + quad) * 8];
        short8 B0 = *(const short8*)(B0p + kt * 32);
        short8 B1 = *(const short8*)(B1p + kt * 32);
        acc0 = __builtin_amdgcn_mfma_f32_16x16x32_bf16(A, B0, acc0, 0, 0, 0);
        acc1 = __builtin_amdgcn_mfma_f32_16x16x32_bf16(A, B1, acc1, 0, 0, 0);
    }

    const float bv0 = bias[c0 + r16];
    const float bv1 = bias[c0 + 16 + r16];
#pragma unroll
    for (int r = 0; r < 4; r++) {
        const size_t row = (size_t)(pbase + quad * 4 + r) * COUT;
        out[row + c0 + r16]      = acc0[r] + bv0;
        out[row + c0 + 16 + r16] = acc1[r] + bv1;
    }
}

// Fallback if ws can't hold the 278 KB padded LW (shouldn't happen): all-fp32,
// one block per point. Slow but correct.
__global__ __launch_bounds__(256) void fused_fallback_kernel(
    const float* __restrict__ inp, const int* __restrict__ nbr,
    const float* __restrict__ wn, const float* __restrict__ addl,
    const float* __restrict__ lw, const float* __restrict__ bias,
    float* __restrict__ out)
{
    const int p = blockIdx.x;
    const int b = p / NPERB;
    const int tid = threadIdx.x;
    __shared__ float sf[KNBR * CF];
    __shared__ float sw[KNBR * MDIM];
    __shared__ float sp[KF];

    sw[tid] = wn[(size_t)p * (KNBR * MDIM) + tid];
    for (int i = tid; i < KNBR * CIN; i += 256) {
        int k = i >> 6, c = i & 63;
        int idx = nbr[(size_t)p * KNBR + k];
        sf[k * CF + c] = inp[((size_t)b * NPERB + idx) * CIN + c];
    }
    if (tid < KNBR * CADD) {
        int k = tid / CADD, c = tid - k * CADD;
        sf[k * CF + CIN + c] = addl[(size_t)p * (KNBR * CADD) + tid];
    }
    __syncthreads();
    for (int f = tid; f < KF; f += 256) {
        int c = f >> 4, m = f & 15;
        float s = 0;
#pragma unroll
        for (int k = 0; k < KNBR; k++) s += sf[k * CF + c] * sw[k * MDIM + m];
        sp[f] = s;
    }
    __syncthreads();
    const int o = tid >> 1, h = tid & 1;
    float s = 0;
    for (int f = h * (KF / 2); f < (h + 1) * (KF / 2); f++)
        s += sp[f] * lw[(size_t)o * KF + f];
    s += __shfl_xor(s, 1);
    if (h == 0) out[(size_t)p * COUT + o] = s + bias[o];
}

extern "C" void kernel_launch(void* const* d_in, const int* in_sizes, int n_in,
                              void* d_out, int out_size, void* d_ws, size_t ws_size,
                              hipStream_t stream) {
    const float* inp  = (const float*)d_in[0];
    const int*   nbr  = (const int*)d_in[1];
    // d_in[2..4] = inverse_* (backward-only, unused)
    const float* wn   = (const float*)d_in[5];
    const float* addl = (const float*)d_in[6];
    const float* lw   = (const float*)d_in[7];
    const float* bias = (const float*)d_in[8];
    float* out = (float*)d_out;

    const size_t lw_bytes = (size_t)COUT * KP * sizeof(u16);  // 278528
    if (ws_size < lw_bytes) {
        fused_fallback_kernel<<<NPTS, 256, 0, stream>>>(inp, nbr, wn, addl, lw, bias, out);
        return;
    }
    u16* lwp = (u16*)d_ws;
    prep_lw_kernel<<<(COUT * KP + 255) / 256, 256, 0, stream>>>(lw, lwp);
    fused_kernel<<<NPTS / PTSB, 256, 0, stream>>>(inp, nbr, wn, addl, lwp, bias, out);
}

// Round 5
// 357.556 us; speedup vs baseline: 1.0943x; 1.0943x over previous
//
#include <hip/hip_runtime.h>
#include <stdint.h>

typedef unsigned short u16;
typedef short short8 __attribute__((ext_vector_type(8)));
typedef float floatx4 __attribute__((ext_vector_type(4)));

#define NPERB   40000
#define NPTS    80000
#define KNBR    16
#define CIN     64
#define MDIM    16
#define CADD    3
#define CF      (CIN + CADD)
#define COUT    128
#define KF      1072
#define KP      1088
#define NKT     34        // KP/32 K-steps
#define PTSB    32        // points per block
#define SLAB    129       // chunks per kt slab: 32 rows x 4 quads + 1 pad (odd)

__device__ __forceinline__ u16 f2bf(float f) {
    union { float f; unsigned int u; } v; v.f = f;
    unsigned int u = v.u;
    return (u16)((u + 0x7FFFu + ((u >> 16) & 1u)) >> 16);
}
__device__ __forceinline__ short8 pack8(floatx4 x, floatx4 y) {
    union { short8 v; u16 a[8]; } u;
    u.a[0] = f2bf(x[0]); u.a[1] = f2bf(x[1]); u.a[2] = f2bf(x[2]); u.a[3] = f2bf(x[3]);
    u.a[4] = f2bf(y[0]); u.a[5] = f2bf(y[1]); u.a[6] = f2bf(y[2]); u.a[7] = f2bf(y[3]);
    return u.v;
}
// 16B-chunk XOR swizzle: spreads bank columns; bijective (involution on low 3 bits).
__device__ __forceinline__ unsigned swz(unsigned chunk) {
    return chunk ^ ((chunk >> 3) & 7u);
}

// Convert+pad linear_weight fp32 [128,1072] -> bf16 ws [128,1088] (zero pad).
__global__ void prep_lw_kernel(const float* __restrict__ lw, u16* __restrict__ lwp) {
    int i = blockIdx.x * 256 + threadIdx.x;
    if (i >= COUT * KP) return;
    int o = i / KP, f = i - o * KP;
    lwp[i] = (f < KF) ? f2bf(lw[(size_t)o * KF + f]) : (u16)0;
}

// Fused: phase 1 builds pconv for 32 points directly in LDS (MFMA-A chunk
// layout, XOR-swizzled); phase 2 does [32 x 1088] x [1088 x 128] with bf16 MFMA.
// Chunk (kt, pr, quad) holds pconv[pr][f = kt*32 + quad*8 .. +7] as 8 bf16.
// wn/nbr reads are wave-uniform (readfirstlane'd point) -> SMEM s_loads feeding
// v_fmac SGPR operands: no LDS broadcast, no per-lane wn replication.
__global__ __launch_bounds__(512) void fused_kernel(
    const float* __restrict__ inp,   // [2,40000,64] fp32
    const int*   __restrict__ nbr,   // [2,40000,16] int32
    const float* __restrict__ wn,    // [2,40000,16,16] fp32
    const float* __restrict__ addl,  // [2,40000,16,3] fp32
    const u16*   __restrict__ lwp,   // [128,1088] bf16 (padded)
    const float* __restrict__ bias,  // [128] fp32
    float* __restrict__ out)         // [80000,128] fp32
{
    __shared__ __align__(16) u16 Apc[(NKT * SLAB + 8) * 8];   // 70304 B (+swz margin)

    const int wave = threadIdx.x >> 6;
    const int lane = threadIdx.x & 63;
    const int pbase = blockIdx.x * PTSB;        // batch boundary 40000 % 32 == 0
    const float* inpb = inp + ((pbase >= NPERB) ? (size_t)NPERB * CIN : 0);

    // ---------------- phase 1: pconv -> LDS ----------------
    const int em = lane & 15, ec = lane >> 4;   // extra-channel mapping
    for (int i = 0; i < PTSB / 8; i++) {        // 4 points per wave
        const int pr = wave * 4 + i;            // point row 0..31
        const int p  = __builtin_amdgcn_readfirstlane(pbase + pr);
        const float* wp  = wn  + (size_t)p * (KNBR * MDIM);
        const int*  nbrp = nbr + (size_t)p * KNBR;

        // additional_features (48 floats) live in lanes 0..47
        float av_hold = (lane < KNBR * CADD)
                          ? addl[(size_t)p * (KNBR * CADD) + lane] : 0.f;

        // per-lane wn[k][em] for the extra-channel path (quad-broadcast b32s)
        float wv[KNBR];
#pragma unroll
        for (int k = 0; k < KNBR; k++) wv[k] = wp[k * MDIM + em];

        // extra channels 64..66 (67 = zero pad): lane -> (c=64+ec, m=em)
        {
            float ev = 0.f;
#pragma unroll
            for (int k = 0; k < KNBR; k++)
                ev += __shfl(av_hold, k * CADD + ec) * wv[k];
            if (ec == 3) ev = 0.f;              // channel 67 + f>=1072 pad
            unsigned kt   = 32 + (lane >> 5);
            unsigned quad = (lane >> 3) & 3;
            unsigned ch   = kt * SLAB + (unsigned)pr * 4 + quad;
            Apc[swz(ch) * 8 + (lane & 7)] = f2bf(ev);
        }

        // main channels: lane = c (0..63); wn via uniform (SMEM) loads
        const floatx4* wp4 = (const floatx4*)wp;
        floatx4 a0 = 0, a1 = 0, a2 = 0, a3 = 0;
#pragma unroll
        for (int k = 0; k < KNBR; k++) {
            int idx = nbrp[k];                             // uniform -> s_load
            float fv = inpb[(size_t)idx * CIN + lane];     // coalesced 256B/wave
            floatx4 w0 = wp4[k * 4 + 0];                   // uniform -> s_load
            floatx4 w1 = wp4[k * 4 + 1];
            floatx4 w2 = wp4[k * 4 + 2];
            floatx4 w3 = wp4[k * 4 + 3];
            a0 += fv * w0; a1 += fv * w1; a2 += fv * w2; a3 += fv * w3;
        }
        {
            unsigned kt = lane >> 1, qb = (lane & 1) * 2;
            unsigned ch = kt * SLAB + (unsigned)pr * 4 + qb;
            *(short8*)&Apc[swz(ch) * 8]     = pack8(a0, a1);   // m 0..7
            *(short8*)&Apc[swz(ch + 1) * 8] = pack8(a2, a3);   // m 8..15
        }
    }
    __syncthreads();

    // ---------------- phase 2: GEMM [32 x KP] x [KP x 128] ----------------
    // wave tile: 16 points (rowtile = wave&1) x 32 cols (c0 = (wave>>1)*32).
    // mfma_f32_16x16x32_bf16: A[i=lane&15][k=quad*8+j], B[k=quad*8+j][n=lane&15],
    // D[row=quad*4+r][col=lane&15]  (m89/m91-verified).
    const int r16 = lane & 15, quad = lane >> 4;
    const int rt = wave & 1;
    const int c0 = (wave >> 1) * 32;
    const u16* B0p = lwp + (size_t)(c0 + r16) * KP + quad * 8;
    const u16* B1p = B0p + (size_t)16 * KP;
    const unsigned abase = (unsigned)(rt * 16 + r16) * 4 + quad;

    floatx4 acc0 = 0, acc1 = 0;
#pragma unroll 2
    for (int kt = 0; kt < NKT; kt++) {
        short8 A  = *(const short8*)&Apc[swz((unsigned)kt * SLAB + abase) * 8];
        short8 B0 = *(const short8*)(B0p + kt * 32);
        short8 B1 = *(const short8*)(B1p + kt * 32);
        acc0 = __builtin_amdgcn_mfma_f32_16x16x32_bf16(A, B0, acc0, 0, 0, 0);
        acc1 = __builtin_amdgcn_mfma_f32_16x16x32_bf16(A, B1, acc1, 0, 0, 0);
    }

    const float bv0 = bias[c0 + r16];
    const float bv1 = bias[c0 + 16 + r16];
#pragma unroll
    for (int r = 0; r < 4; r++) {
        const size_t row = (size_t)(pbase + rt * 16 + quad * 4 + r) * COUT;
        out[row + c0 + r16]      = acc0[r] + bv0;
        out[row + c0 + 16 + r16] = acc1[r] + bv1;
    }
}

// Fallback if ws can't hold the 278 KB padded LW (shouldn't happen): all-fp32,
// one block per point. Slow but correct.
__global__ __launch_bounds__(256) void fused_fallback_kernel(
    const float* __restrict__ inp, const int* __restrict__ nbr,
    const float* __restrict__ wn, const float* __restrict__ addl,
    const float* __restrict__ lw, const float* __restrict__ bias,
    float* __restrict__ out)
{
    const int p = blockIdx.x;
    const int b = p / NPERB;
    const int tid = threadIdx.x;
    __shared__ float sf[KNBR * CF];
    __shared__ float sw[KNBR * MDIM];
    __shared__ float sp[KF];

    sw[tid] = wn[(size_t)p * (KNBR * MDIM) + tid];
    for (int i = tid; i < KNBR * CIN; i += 256) {
        int k = i >> 6, c = i & 63;
        int idx = nbr[(size_t)p * KNBR + k];
        sf[k * CF + c] = inp[((size_t)b * NPERB + idx) * CIN + c];
    }
    if (tid < KNBR * CADD) {
        int k = tid / CADD, c = tid - k * CADD;
        sf[k * CF + CIN + c] = addl[(size_t)p * (KNBR * CADD) + tid];
    }
    __syncthreads();
    for (int f = tid; f < KF; f += 256) {
        int c = f >> 4, m = f & 15;
        float s = 0;
#pragma unroll
        for (int k = 0; k < KNBR; k++) s += sf[k * CF + c] * sw[k * MDIM + m];
        sp[f] = s;
    }
    __syncthreads();
    const int o = tid >> 1, h = tid & 1;
    float s = 0;
    for (int f = h * (KF / 2); f < (h + 1) * (KF / 2); f++)
        s += sp[f] * lw[(size_t)o * KF + f];
    s += __shfl_xor(s, 1);
    if (h == 0) out[(size_t)p * COUT + o] = s + bias[o];
}

extern "C" void kernel_launch(void* const* d_in, const int* in_sizes, int n_in,
                              void* d_out, int out_size, void* d_ws, size_t ws_size,
                              hipStream_t stream) {
    const float* inp  = (const float*)d_in[0];
    const int*   nbr  = (const int*)d_in[1];
    // d_in[2..4] = inverse_* (backward-only, unused)
    const float* wn   = (const float*)d_in[5];
    const float* addl = (const float*)d_in[6];
    const float* lw   = (const float*)d_in[7];
    const float* bias = (const float*)d_in[8];
    float* out = (float*)d_out;

    const size_t lw_bytes = (size_t)COUT * KP * sizeof(u16);  // 278528
    if (ws_size < lw_bytes) {
        fused_fallback_kernel<<<NPTS, 256, 0, stream>>>(inp, nbr, wn, addl, lw, bias, out);
        return;
    }
    u16* lwp = (u16*)d_ws;
    prep_lw_kernel<<<(COUT * KP + 255) / 256, 256, 0, stream>>>(lw, lwp);
    fused_kernel<<<NPTS / PTSB, 512, 0, stream>>>(inp, nbr, wn, addl, lwp, bias, out);
}